// Round 2
// baseline (386.667 us; speedup 1.0000x reference)
//
#include <hip/hip_runtime.h>

#define NN 100000
#define NE 1600000
#define NBK 391  // buckets of 256 nodes
#define BSH 8    // bucket = dst >> 8
#define MPAD 100096  // NN padded to 128-row tiles (782*128)
#define SCB 391      // ceil(NE/4096) scatter blocks
#define CAP 5120     // padded slots per bucket (expected max ~4.3K)
#define NB64 1563    // ceil(NN/64) fused agg+gemm blocks

typedef unsigned short ushortT;
typedef unsigned long long ull;
using sh8 = __attribute__((ext_vector_type(8))) short;   // 8 bf16 (4 VGPR) MFMA frag
using f4  = __attribute__((ext_vector_type(4))) float;   // MFMA accumulator

// ---------------- bf16 helpers ----------------

__device__ __forceinline__ unsigned short bfr(float f) {
  unsigned u = __float_as_uint(f);
  u += 0x7FFF + ((u >> 16) & 1);
  return (unsigned short)(u >> 16);
}
__device__ __forceinline__ float bf2f(unsigned short h) {
  return __uint_as_float(((unsigned)h) << 16);
}
__device__ __forceinline__ void acc8(const uint4 v, float* a) {
  a[0] += __uint_as_float(v.x << 16);
  a[1] += __uint_as_float(v.x & 0xFFFF0000u);
  a[2] += __uint_as_float(v.y << 16);
  a[3] += __uint_as_float(v.y & 0xFFFF0000u);
  a[4] += __uint_as_float(v.z << 16);
  a[5] += __uint_as_float(v.z & 0xFFFF0000u);
  a[6] += __uint_as_float(v.w << 16);
  a[7] += __uint_as_float(v.w & 0xFFFF0000u);
}
__device__ __forceinline__ sh8 hi8(const float4 a, const float4 b) {
  sh8 r;
  r[0] = (short)bfr(a.x); r[1] = (short)bfr(a.y);
  r[2] = (short)bfr(a.z); r[3] = (short)bfr(a.w);
  r[4] = (short)bfr(b.x); r[5] = (short)bfr(b.y);
  r[6] = (short)bfr(b.z); r[7] = (short)bfr(b.w);
  return r;
}

// ---------------- W pack helper ----------------
// Bp[((ks*CG + g)*64 + lane)*8 + j]; k=(ks&3)*32+(lane>>4)*8+j, n=g*16+(lane&15)
// hi for ks<4, lo residue for ks>=4.  (W stays split: keeps the weight error
// term at 2^-18 while activations carry the accepted 2^-9.)

template <int COUT>
__device__ __forceinline__ void packone(const float* __restrict__ W,
                                        ushortT* __restrict__ Bp, int i) {
  const int j = i & 7;
  const int l = (i >> 3) & 63;
  const int rest = i >> 9;
  const int g = rest % (COUT / 16);
  const int ks = rest / (COUT / 16);
  const int k = (ks & 3) * 32 + (l >> 4) * 8 + j;
  const int n = g * 16 + (l & 15);
  const float v = W[k * COUT + n];
  const unsigned short h = bfr(v);
  Bp[i] = (ks < 4) ? h : bfr(v - bf2f(h));
}

// ---------------- fused scatter (padded buckets) + weight pack ---------------
// Pairs packed to 4 B: (src << 8) | (dst & 255). src < 2^17, off 8 bits.

__global__ __launch_bounds__(256) void k_scatterpack(
    const int* __restrict__ src, const int* __restrict__ dst,
    int* __restrict__ cursor, unsigned* __restrict__ pairArr,
    const float* __restrict__ W1, const float* __restrict__ W2,
    const float* __restrict__ W3, ushortT* __restrict__ Bp1,
    ushortT* __restrict__ Bp2, ushortT* __restrict__ Bp3) {
  if (blockIdx.x >= SCB) {
    const int i = (blockIdx.x - SCB) * 256 + threadIdx.x;  // 0..81919
    if (i < 32768) packone<128>(W1, Bp1, i);
    else if (i < 65536) packone<128>(W2, Bp2, i - 32768);
    else packone<64>(W3, Bp3, i - 65536);
    return;
  }
  __shared__ int lcnt[512];   // NBK padded to 512 (zeros beyond) for paired scan
  __shared__ int lbase[512];
  __shared__ int lrank[NBK];
  __shared__ int bbase[NBK];
  __shared__ int sd2[256];
  __shared__ unsigned sorted[4096];
  __shared__ int target[4096];
  const int t = threadIdx.x;
  for (int i = t; i < 512; i += 256) lcnt[i] = 0;
  for (int i = t; i < NBK; i += 256) lrank[i] = 0;
  __syncthreads();
  const int base = blockIdx.x * 4096;
  int rs[16], rd[16];
#pragma unroll
  for (int q = 0; q < 16; q++) {
    int e = base + t + 256 * q;
    rs[q] = (e < NE) ? src[e] : -1;
    rd[q] = (e < NE) ? dst[e] : -1;
    if (rd[q] >= 0) atomicAdd(&lcnt[rd[q] >> BSH], 1);
  }
  __syncthreads();
  // 256-wide paired exclusive scan of lcnt[0..511]
  const int s0 = lcnt[2 * t];
  const int s1 = lcnt[2 * t + 1];
  sd2[t] = s0 + s1;
  __syncthreads();
  for (int off = 1; off < 256; off <<= 1) {
    int x = (t >= off) ? sd2[t - off] : 0;
    __syncthreads();
    sd2[t] += x;
    __syncthreads();
  }
  const int epair = sd2[t] - (s0 + s1);
  lbase[2 * t] = epair;
  lbase[2 * t + 1] = epair + s0;
  __syncthreads();
  for (int i = t; i < NBK; i += 256)
    if (lcnt[i] > 0) bbase[i] = atomicAdd(&cursor[i], lcnt[i]);
  __syncthreads();
#pragma unroll
  for (int q = 0; q < 16; q++) {
    if (rd[q] >= 0) {
      int b = rd[q] >> BSH;
      int r = atomicAdd(&lrank[b], 1);
      int slot = lbase[b] + r;
      sorted[slot] = ((unsigned)rs[q] << 8) | ((unsigned)rd[q] & 255u);
      target[slot] = b * CAP + bbase[b] + r;  // padded-bucket placement
    }
  }
  __syncthreads();
  const int n = min(4096, NE - base);
  for (int s = t; s < n; s += 256) pairArr[target[s]] = sorted[s];
}

// ---------------- CSR build: one block (256 thr) per 256-node bucket ---------
// thread t owns node n0+t. Count via LDS atomics, 256-wide Hillis-Steele
// scan for intra-bucket offsets, then col fill via LDS cursors.

__global__ __launch_bounds__(256) void k_buildcsr(const unsigned* __restrict__ pairArr,
                                                  const int* __restrict__ cnt,
                                                  float* __restrict__ dinv,
                                                  int* __restrict__ rowptr,
                                                  int* __restrict__ col) {
  __shared__ int lc[256];
  __shared__ int sd[256];
  __shared__ int bc[NBK];
  const int t = threadIdx.x;
  const int b = blockIdx.x;
  const int n0 = b << BSH;
  for (int i = t; i < NBK; i += 256) bc[i] = cnt[i];
  lc[t] = 0;
  __syncthreads();
  // ebeg = sum of bucket counts before b (parallel partial + tree reduce)
  int partial = 0;
  for (int i = t; i < b; i += 256) partial += bc[i];
  sd[t] = partial;
  __syncthreads();
  for (int off = 128; off > 0; off >>= 1) {
    if (t < off) sd[t] += sd[t + off];
    __syncthreads();
  }
  const int ebeg = sd[0];
  const int myCnt = bc[b];
  __syncthreads();
  const unsigned* pb = pairArr + (size_t)b * CAP;
  for (int i = t; i < myCnt; i += 256)
    atomicAdd(&lc[pb[i] & 255u], 1);
  __syncthreads();
  const int v = lc[t];
  sd[t] = v;
  __syncthreads();
  for (int off = 1; off < 256; off <<= 1) {
    int x = (t >= off) ? sd[t - off] : 0;
    __syncthreads();
    sd[t] += x;
    __syncthreads();
  }
  const int excl = sd[t] - v;  // exclusive within bucket
  lc[t] = excl;                // cursor
  const int node = n0 + t;
  if (node < NN) {
    rowptr[node] = ebeg + excl;
    dinv[node] = rsqrtf(1.0f + (float)v);  // self-loop => deg >= 1
  }
  if (b == 0 && t == 0) rowptr[NN] = NE;
  __syncthreads();
  for (int i = t; i < myCnt; i += 256) {
    unsigned p = pb[i];
    int d = (int)(p & 255u);
    int srcv = (int)(p >> 8);
    int pos = atomicAdd(&lc[d], 1);
    col[ebeg + pos] = srcv;
  }
}

// ---------------- MFMA GEMM (layer 1): hs1 = bf16( X @ W1 * dinv ) -----------
// Reads fp32 X directly, rounds to bf16 in-reg. W split hi/lo, 2-pass per
// 32-wide K chunk. RG=2, CG=4. Frag layouts: A m=lane&15, k=quad*8+j [m120];
// B n=lane&15 [m97]; C/D col=lane&15,row=quad*4+reg [m89].

template <int COUT, bool FUSED>
__global__ __launch_bounds__(256) void k_gemmM(const ushortT* __restrict__ A,
                                               const float* __restrict__ X,
                                               const ushortT* __restrict__ Bp,
                                               const float* __restrict__ dinv,
                                               ushortT* __restrict__ hs) {
  constexpr int CGALL = COUT / 16;              // 8 or 4
  constexpr int RG = 2;                         // row-groups per wave (32 rows)
  constexpr int CG = 4;                         // col-groups per wave (64 cols)
  const int w = threadIdx.x >> 6;
  const int lane = threadIdx.x & 63;
  const int q = lane >> 4;
  const int c = lane & 15;
  int row0, cg0;
  if (COUT == 128) {
    row0 = blockIdx.x * 64 + (w & 1) * 32;     // block: 64 rows x 128 cols
    cg0 = (w >> 1) * 4;
  } else {
    row0 = blockIdx.x * 128 + w * 32;          // block: 128 rows x 64 cols
    cg0 = 0;
  }

  const ushortT* ap[RG];
  const float* xp[RG];
#pragma unroll
  for (int rg = 0; rg < RG; rg++) {
    const int row = row0 + rg * 16 + c;
    if (FUSED) xp[rg] = X + (size_t)min(row, NN - 1) * 128 + q * 8;
    else ap[rg] = A + (size_t)row * 128 + q * 8;
  }
  const ushortT* bp0 = Bp + (size_t)lane * 8;

  f4 acc[RG][CG];
#pragma unroll
  for (int i = 0; i < RG; i++)
#pragma unroll
    for (int j = 0; j < CG; j++) acc[i][j] = (f4){0.f, 0.f, 0.f, 0.f};

  sh8 ah[RG], bh[CG], bl[CG];
  sh8 nah[RG], nbh[CG], nbl[CG];

  auto loadA = [&](int kr, sh8 (&h)[RG]) {
#pragma unroll
    for (int rg = 0; rg < RG; rg++) {
      if (FUSED) {
        const float4 x0 = *reinterpret_cast<const float4*>(xp[rg] + kr * 32);
        const float4 x1 = *reinterpret_cast<const float4*>(xp[rg] + kr * 32 + 4);
        h[rg] = hi8(x0, x1);
      } else {
        h[rg] = *reinterpret_cast<const sh8*>(ap[rg] + kr * 32);
      }
    }
  };
  auto loadB = [&](int kr, sh8 (&h)[CG], sh8 (&l)[CG]) {
#pragma unroll
    for (int cg = 0; cg < CG; cg++) {
      h[cg] = *reinterpret_cast<const sh8*>(bp0 + (size_t)(kr * CGALL + cg0 + cg) * 512);
      l[cg] = *reinterpret_cast<const sh8*>(bp0 + (size_t)((4 + kr) * CGALL + cg0 + cg) * 512);
    }
  };

  loadA(0, ah);
  loadB(0, bh, bl);
#pragma unroll
  for (int kr = 0; kr < 4; kr++) {
    if (kr < 3) {
      loadA(kr + 1, nah);
      loadB(kr + 1, nbh, nbl);
    }
#pragma unroll
    for (int rg = 0; rg < RG; rg++)
#pragma unroll
      for (int cg = 0; cg < CG; cg++)
        acc[rg][cg] = __builtin_amdgcn_mfma_f32_16x16x32_bf16(ah[rg], bh[cg],
                                                              acc[rg][cg], 0, 0, 0);
#pragma unroll
    for (int rg = 0; rg < RG; rg++)
#pragma unroll
      for (int cg = 0; cg < CG; cg++)
        acc[rg][cg] = __builtin_amdgcn_mfma_f32_16x16x32_bf16(ah[rg], bl[cg],
                                                              acc[rg][cg], 0, 0, 0);
    if (kr < 3) {
#pragma unroll
      for (int rg = 0; rg < RG; rg++) ah[rg] = nah[rg];
#pragma unroll
      for (int cg = 0; cg < CG; cg++) { bh[cg] = nbh[cg]; bl[cg] = nbl[cg]; }
    }
  }

  // epilogue: scale by dinv[row], round to bf16, store
#pragma unroll
  for (int rg = 0; rg < RG; rg++) {
#pragma unroll
    for (int reg = 0; reg < 4; reg++) {
      const int row = row0 + rg * 16 + q * 4 + reg;
      if (row < NN) {
        const float dv = dinv[row];
#pragma unroll
        for (int cg = 0; cg < CG; cg++) {
          hs[(size_t)row * COUT + (cg0 + cg) * 16 + c] = bfr(acc[rg][cg][reg] * dv);
        }
      }
    }
  }
}

// ---------------- FUSED aggregate + next-layer GEMM --------------------------
// Block = 64 nodes, 4 waves; wave w aggregates nodes n0+16w..+15 (one node at
// a time, 4 quads = 4 edges in parallel, 2-deep window — gather is BW-floor'd
// so depth beyond 2 is free but useless [R1]). Result rows A=relu(agg+bias)
// go to a 16 KB LDS tile, bf16, XOR-swizzled byte^=((row&7)<<4) so the GEMM's
// ds_read_b128 per-m-lane reads are 2-way (free, m136) instead of 16-way.
// After one barrier each wave MFMAs its 16 rows x COUT against L2-hot Bp.
// Removes the 25.6 MB A round-trip per junction + one kernel drain.

template <int COUT>
__global__ __launch_bounds__(256) void k_aggemm(
    const ushortT* __restrict__ hs_in, const int* __restrict__ rowptr,
    const int* __restrict__ col, const float* __restrict__ dinv,
    const float* __restrict__ bias, const ushortT* __restrict__ Bp,
    ushortT* __restrict__ hs_out) {
  constexpr int CGALL = COUT / 16;  // 8 or 4
  __shared__ ushortT At[64 * 128];  // 16 KB bf16 tile, swizzled
  const int t = threadIdx.x;
  const int w = t >> 6;
  const int lane = t & 63;
  const int q = lane >> 4;
  const int c = lane & 15;
  const int chb = c * 8;
  const int n0 = blockIdx.x * 64;

  // ---- phase 1: aggregate 16 nodes per wave into LDS ----
  for (int it = 0; it < 16; ++it) {
    const int r = w * 16 + it;  // LDS row 0..63
    const int node = n0 + r;
    float a[8] = {};
    if (node < NN) {  // wave-uniform guard
      const int beg = rowptr[node];
      const int end = rowptr[node + 1];
      if (q == 0) {  // self-loop
        const uint4 v = *reinterpret_cast<const uint4*>(hs_in + (long)node * 128 + chb);
        acc8(v, a);
      }
      int j = beg;
      if (j + 8 <= end) {
        int c0 = col[j + q];
        int c1 = col[j + 4 + q];
        while (true) {
          const uint4 v0 = *reinterpret_cast<const uint4*>(hs_in + (long)c0 * 128 + chb);
          const uint4 v1 = *reinterpret_cast<const uint4*>(hs_in + (long)c1 * 128 + chb);
          j += 8;
          const bool more = (j + 8 <= end);
          int m0, m1;
          if (more) { m0 = col[j + q]; m1 = col[j + 4 + q]; }
          acc8(v0, a);
          acc8(v1, a);
          if (!more) break;
          c0 = m0; c1 = m1;
        }
      }
      if (j + 4 <= end) {
        int cc = col[j + q];
        const uint4 v = *reinterpret_cast<const uint4*>(hs_in + (long)cc * 128 + chb);
        acc8(v, a);
        j += 4;
      }
      {
        const int rem = end - j;  // 0..3
        if (q < rem) {
          int cc = col[j + q];
          const uint4 v = *reinterpret_cast<const uint4*>(hs_in + (long)cc * 128 + chb);
          acc8(v, a);
        }
      }
    }
#pragma unroll
    for (int i = 0; i < 8; i++) a[i] += __shfl(a[i], lane ^ 32);
#pragma unroll
    for (int i = 0; i < 8; i++) a[i] += __shfl(a[i], lane ^ 16);
    if (q == 0 && node < NN) {
      const float di = dinv[node];
      const float4 b0 = *reinterpret_cast<const float4*>(bias + chb);
      const float4 b1 = *reinterpret_cast<const float4*>(bias + chb + 4);
      float o[8];
      o[0] = fmaf(a[0], di, b0.x); o[1] = fmaf(a[1], di, b0.y);
      o[2] = fmaf(a[2], di, b0.z); o[3] = fmaf(a[3], di, b0.w);
      o[4] = fmaf(a[4], di, b1.x); o[5] = fmaf(a[5], di, b1.y);
      o[6] = fmaf(a[6], di, b1.z); o[7] = fmaf(a[7], di, b1.w);
#pragma unroll
      for (int i = 0; i < 8; i++) o[i] = fmaxf(o[i], 0.f);  // relu (layers 1,2)
      uint4 H;
      H.x = (unsigned)bfr(o[0]) | ((unsigned)bfr(o[1]) << 16);
      H.y = (unsigned)bfr(o[2]) | ((unsigned)bfr(o[3]) << 16);
      H.z = (unsigned)bfr(o[4]) | ((unsigned)bfr(o[5]) << 16);
      H.w = (unsigned)bfr(o[6]) | ((unsigned)bfr(o[7]) << 16);
      const unsigned bo = (unsigned)(r * 256 + c * 16) ^ (unsigned)((r & 7) << 4);
      *reinterpret_cast<uint4*>(reinterpret_cast<char*>(At) + bo) = H;
    }
  }
  __syncthreads();

  // ---- phase 2: GEMM, 16 rows per wave x COUT cols ----
  f4 acc[CGALL];
#pragma unroll
  for (int cg = 0; cg < CGALL; ++cg) acc[cg] = (f4){0.f, 0.f, 0.f, 0.f};
  const ushortT* bp0 = Bp + (size_t)lane * 8;
  const int arow = w * 16 + c;  // A-frag row: m = lane&15
  const char* ab = reinterpret_cast<const char*>(At);
#pragma unroll
  for (int kr = 0; kr < 4; ++kr) {
    const unsigned bo =
        (unsigned)(arow * 256 + kr * 64 + q * 16) ^ (unsigned)((arow & 7) << 4);
    const sh8 af = *reinterpret_cast<const sh8*>(ab + bo);
    sh8 bh[CGALL];
#pragma unroll
    for (int cg = 0; cg < CGALL; ++cg)
      bh[cg] = *reinterpret_cast<const sh8*>(bp0 + (size_t)(kr * CGALL + cg) * 512);
#pragma unroll
    for (int cg = 0; cg < CGALL; ++cg)
      acc[cg] = __builtin_amdgcn_mfma_f32_16x16x32_bf16(af, bh[cg], acc[cg], 0, 0, 0);
#pragma unroll
    for (int cg = 0; cg < CGALL; ++cg)
      bh[cg] = *reinterpret_cast<const sh8*>(bp0 + (size_t)((4 + kr) * CGALL + cg) * 512);
#pragma unroll
    for (int cg = 0; cg < CGALL; ++cg)
      acc[cg] = __builtin_amdgcn_mfma_f32_16x16x32_bf16(af, bh[cg], acc[cg], 0, 0, 0);
  }
  // epilogue: scale by dinv[row] (pre-scale for next agg), round, store
#pragma unroll
  for (int reg = 0; reg < 4; ++reg) {
    const int row = n0 + w * 16 + q * 4 + reg;  // C/D row = quad*4+reg [m89]
    if (row < NN) {
      const float dv = dinv[row];
#pragma unroll
      for (int cg = 0; cg < CGALL; ++cg)
        hs_out[(size_t)row * COUT + cg * 16 + c] = bfr(acc[cg][reg] * dv);
    }
  }
}

// ---------------- final aggregation (64 ch, fp32 out) ------------------------

__global__ __launch_bounds__(256) void k_agg64(const ushortT* __restrict__ hs,
                                               const int* __restrict__ rowptr,
                                               const int* __restrict__ col,
                                               const float* __restrict__ dinv,
                                               const float* __restrict__ bias,
                                               float* __restrict__ out) {
  const int gid = blockIdx.x * 256 + threadIdx.x;
  const int node = gid >> 6;
  if (node >= NN) return;
  const int lane = threadIdx.x & 63;
  const int o8 = lane >> 3;        // eighth 0..7
  const int chb = (lane & 7) * 8;  // 8 channels per lane
  const int beg = rowptr[node];
  const int end = rowptr[node + 1];

  float a[8] = {};
  if (o8 == 0) {  // self
    const uint4 v = *reinterpret_cast<const uint4*>(hs + (long)node * 64 + chb);
    acc8(v, a);
  }

  int j = beg;
  if (j + 16 <= end) {
    int c0 = col[j + o8];
    int c1 = col[j + 8 + o8];
    while (true) {
      const uint4 v0 = *reinterpret_cast<const uint4*>(hs + (long)c0 * 64 + chb);
      const uint4 v1 = *reinterpret_cast<const uint4*>(hs + (long)c1 * 64 + chb);
      j += 16;
      const bool more = (j + 16 <= end);
      int n0, n1;
      if (more) { n0 = col[j + o8]; n1 = col[j + 8 + o8]; }
      acc8(v0, a);
      acc8(v1, a);
      if (!more) break;
      c0 = n0; c1 = n1;
    }
  }
  for (; j + 8 <= end; j += 8) {
    int c = col[j + o8];
    const uint4 v = *reinterpret_cast<const uint4*>(hs + (long)c * 64 + chb);
    acc8(v, a);
  }
  {
    const int r = end - j;  // 0..7
    if (o8 < r) {
      int c = col[j + o8];
      const uint4 v = *reinterpret_cast<const uint4*>(hs + (long)c * 64 + chb);
      acc8(v, a);
    }
  }

#pragma unroll
  for (int i = 0; i < 8; i++) a[i] += __shfl(a[i], lane ^ 32);
#pragma unroll
  for (int i = 0; i < 8; i++) a[i] += __shfl(a[i], lane ^ 16);
#pragma unroll
  for (int i = 0; i < 8; i++) a[i] += __shfl(a[i], lane ^ 8);

  if (o8 == 0) {
    const float di = dinv[node];
    const float4 b0 = *reinterpret_cast<const float4*>(bias + chb);
    const float4 b1 = *reinterpret_cast<const float4*>(bias + chb + 4);
    float4 r0, r1;
    r0.x = fmaf(a[0], di, b0.x); r0.y = fmaf(a[1], di, b0.y);
    r0.z = fmaf(a[2], di, b0.z); r0.w = fmaf(a[3], di, b0.w);
    r1.x = fmaf(a[4], di, b1.x); r1.y = fmaf(a[5], di, b1.y);
    r1.z = fmaf(a[6], di, b1.z); r1.w = fmaf(a[7], di, b1.w);
    *reinterpret_cast<float4*>(out + (long)node * 64 + chb) = r0;
    *reinterpret_cast<float4*>(out + (long)node * 64 + chb + 4) = r1;
  }
}

// ---------------- launch ----------------

extern "C" void kernel_launch(void* const* d_in, const int* in_sizes, int n_in,
                              void* d_out, int out_size, void* d_ws, size_t ws_size,
                              hipStream_t stream) {
  const float* x  = (const float*)d_in[0];
  const int* ei   = (const int*)d_in[1];
  const float* W1 = (const float*)d_in[2];
  const float* b1 = (const float*)d_in[3];
  const float* W2 = (const float*)d_in[4];
  const float* b2 = (const float*)d_in[5];
  const float* W3 = (const float*)d_in[6];
  const float* b3 = (const float*)d_in[7];
  float* out = (float*)d_out;
  const int* srcp = ei;        // edge_index[0]
  const int* dstp = ei + NE;   // edge_index[1]

  char* wsb = (char*)d_ws;
  size_t off = 0;
  auto alloc = [&](size_t bytes) -> void* {
    void* p = wsb + off;
    off += (bytes + 255) & ~(size_t)255;
    return p;
  };
  ushortT* hs1 = (ushortT*)alloc((size_t)MPAD * 128 * 2);  // bf16 layer-1 transform
  ushortT* hs2 = (ushortT*)alloc((size_t)NN * 128 * 2);    // bf16 layer-2 transform
  int*   col    = (int*)alloc((size_t)NE * 4);
  int*   rowptr = (int*)alloc((size_t)(NN + 1) * 4);
  float* dinv   = (float*)alloc((size_t)NN * 4);
  int*   cursor = (int*)alloc((size_t)NBK * 4);
  ushortT* Bp1 = (ushortT*)alloc((size_t)32768 * 2);  // 8 seg x 8 cg x 512
  ushortT* Bp2 = (ushortT*)alloc((size_t)32768 * 2);
  ushortT* Bp3 = (ushortT*)alloc((size_t)16384 * 2);  // 8 seg x 4 cg x 512
  // Aliases (sequential-kernel lifetimes):
  //   pairArr (391*5120*4 = 8 MB) lives in hs2: written K1, read K2,
  //     clobbered by k_aggemm<128>'s hs2 write (K4, after CSR done).
  //   hs3 (NN*64*2 = 12.8 MB) lives in hs1: hs1 dead after k_aggemm<128>
  //     reads it; k_aggemm<64> then writes hs3 there, k_agg64 reads it.
  unsigned* pairArr = (unsigned*)hs2;
  ushortT* hs3 = hs1;
  (void)ws_size; (void)in_sizes; (void)n_in; (void)out_size;

  hipMemsetAsync(cursor, 0, (size_t)NBK * 4, stream);
  k_scatterpack<<<SCB + 320, 256, 0, stream>>>(srcp, dstp, cursor, pairArr,
                                               W1, W2, W3, Bp1, Bp2, Bp3);
  k_buildcsr<<<NBK, 256, 0, stream>>>(pairArr, cursor, dinv, rowptr, col);

  const int aggGrid = (NN * 64) / 256;   // 25000
  const int gemmGrid128 = MPAD / 64;     // 1564 (64-row blocks)

  // layer 1 transform (fused X read)
  k_gemmM<128, true><<<gemmGrid128, 256, 0, stream>>>(nullptr, x, Bp1, dinv, hs1);
  // agg layer1 + transform layer2 (fused)
  k_aggemm<128><<<NB64, 256, 0, stream>>>(hs1, rowptr, col, dinv, b1, Bp2, hs2);
  // agg layer2 + transform layer3 (fused, 128 -> 64)
  k_aggemm<64><<<NB64, 256, 0, stream>>>(hs2, rowptr, col, dinv, b2, Bp3, hs3);
  // final aggregation (no relu, fp32 out)
  k_agg64<<<aggGrid, 256, 0, stream>>>(hs3, rowptr, col, dinv, b3, out);
}

// Round 3
// 370.059 us; speedup vs baseline: 1.0449x; 1.0449x over previous
//
#include <hip/hip_runtime.h>

#define NN 100000
#define NE 1600000
#define NBK 391  // buckets of 256 nodes
#define BSH 8    // bucket = dst >> 8
#define MPAD 100096  // NN padded to 128-row tiles (782*128)
#define SCB 391      // ceil(NE/4096) scatter blocks
#define CAP 5120     // padded slots per bucket (expected max ~4.3K)
#define NB64 1563    // ceil(NN/64) fused agg+gemm blocks

typedef unsigned short ushortT;
typedef unsigned long long ull;
using sh8 = __attribute__((ext_vector_type(8))) short;   // 8 bf16 (4 VGPR) MFMA frag
using f4  = __attribute__((ext_vector_type(4))) float;   // MFMA accumulator

// ---------------- bf16 helpers ----------------

__device__ __forceinline__ unsigned short bfr(float f) {
  unsigned u = __float_as_uint(f);
  u += 0x7FFF + ((u >> 16) & 1);
  return (unsigned short)(u >> 16);
}
__device__ __forceinline__ float bf2f(unsigned short h) {
  return __uint_as_float(((unsigned)h) << 16);
}
__device__ __forceinline__ void acc8(const uint4 v, float* a) {
  a[0] += __uint_as_float(v.x << 16);
  a[1] += __uint_as_float(v.x & 0xFFFF0000u);
  a[2] += __uint_as_float(v.y << 16);
  a[3] += __uint_as_float(v.y & 0xFFFF0000u);
  a[4] += __uint_as_float(v.z << 16);
  a[5] += __uint_as_float(v.z & 0xFFFF0000u);
  a[6] += __uint_as_float(v.w << 16);
  a[7] += __uint_as_float(v.w & 0xFFFF0000u);
}
__device__ __forceinline__ sh8 hi8(const float4 a, const float4 b) {
  sh8 r;
  r[0] = (short)bfr(a.x); r[1] = (short)bfr(a.y);
  r[2] = (short)bfr(a.z); r[3] = (short)bfr(a.w);
  r[4] = (short)bfr(b.x); r[5] = (short)bfr(b.y);
  r[6] = (short)bfr(b.z); r[7] = (short)bfr(b.w);
  return r;
}

// ---------------- W pack helper ----------------
// Bp[((ks*CG + g)*64 + lane)*8 + j]; k=(ks&3)*32+(lane>>4)*8+j, n=g*16+(lane&15)
// hi for ks<4, lo residue for ks>=4.

template <int COUT>
__device__ __forceinline__ void packone(const float* __restrict__ W,
                                        ushortT* __restrict__ Bp, int i) {
  const int j = i & 7;
  const int l = (i >> 3) & 63;
  const int rest = i >> 9;
  const int g = rest % (COUT / 16);
  const int ks = rest / (COUT / 16);
  const int k = (ks & 3) * 32 + (l >> 4) * 8 + j;
  const int n = g * 16 + (l & 15);
  const float v = W[k * COUT + n];
  const unsigned short h = bfr(v);
  Bp[i] = (ks < 4) ? h : bfr(v - bf2f(h));
}

// ---------------- fused scatter (padded buckets) + weight pack ---------------
// Pairs packed to 4 B: (src << 8) | (dst & 255). src < 2^17, off 8 bits.

__global__ __launch_bounds__(256) void k_scatterpack(
    const int* __restrict__ src, const int* __restrict__ dst,
    int* __restrict__ cursor, unsigned* __restrict__ pairArr,
    const float* __restrict__ W1, const float* __restrict__ W2,
    const float* __restrict__ W3, ushortT* __restrict__ Bp1,
    ushortT* __restrict__ Bp2, ushortT* __restrict__ Bp3) {
  if (blockIdx.x >= SCB) {
    const int i = (blockIdx.x - SCB) * 256 + threadIdx.x;  // 0..81919
    if (i < 32768) packone<128>(W1, Bp1, i);
    else if (i < 65536) packone<128>(W2, Bp2, i - 32768);
    else packone<64>(W3, Bp3, i - 65536);
    return;
  }
  __shared__ int lcnt[512];   // NBK padded to 512 (zeros beyond) for paired scan
  __shared__ int lbase[512];
  __shared__ int lrank[NBK];
  __shared__ int bbase[NBK];
  __shared__ int sd2[256];
  __shared__ unsigned sorted[4096];
  __shared__ int target[4096];
  const int t = threadIdx.x;
  for (int i = t; i < 512; i += 256) lcnt[i] = 0;
  for (int i = t; i < NBK; i += 256) lrank[i] = 0;
  __syncthreads();
  const int base = blockIdx.x * 4096;
  int rs[16], rd[16];
#pragma unroll
  for (int q = 0; q < 16; q++) {
    int e = base + t + 256 * q;
    rs[q] = (e < NE) ? src[e] : -1;
    rd[q] = (e < NE) ? dst[e] : -1;
    if (rd[q] >= 0) atomicAdd(&lcnt[rd[q] >> BSH], 1);
  }
  __syncthreads();
  // 256-wide paired exclusive scan of lcnt[0..511]
  const int s0 = lcnt[2 * t];
  const int s1 = lcnt[2 * t + 1];
  sd2[t] = s0 + s1;
  __syncthreads();
  for (int off = 1; off < 256; off <<= 1) {
    int x = (t >= off) ? sd2[t - off] : 0;
    __syncthreads();
    sd2[t] += x;
    __syncthreads();
  }
  const int epair = sd2[t] - (s0 + s1);
  lbase[2 * t] = epair;
  lbase[2 * t + 1] = epair + s0;
  __syncthreads();
  for (int i = t; i < NBK; i += 256)
    if (lcnt[i] > 0) bbase[i] = atomicAdd(&cursor[i], lcnt[i]);
  __syncthreads();
#pragma unroll
  for (int q = 0; q < 16; q++) {
    if (rd[q] >= 0) {
      int b = rd[q] >> BSH;
      int r = atomicAdd(&lrank[b], 1);
      int slot = lbase[b] + r;
      sorted[slot] = ((unsigned)rs[q] << 8) | ((unsigned)rd[q] & 255u);
      target[slot] = b * CAP + bbase[b] + r;  // padded-bucket placement
    }
  }
  __syncthreads();
  const int n = min(4096, NE - base);
  for (int s = t; s < n; s += 256) pairArr[target[s]] = sorted[s];
}

// ---------------- CSR build: one block (256 thr) per 256-node bucket ---------

__global__ __launch_bounds__(256) void k_buildcsr(const unsigned* __restrict__ pairArr,
                                                  const int* __restrict__ cnt,
                                                  float* __restrict__ dinv,
                                                  int* __restrict__ rowptr,
                                                  int* __restrict__ col) {
  __shared__ int lc[256];
  __shared__ int sd[256];
  __shared__ int bc[NBK];
  const int t = threadIdx.x;
  const int b = blockIdx.x;
  const int n0 = b << BSH;
  for (int i = t; i < NBK; i += 256) bc[i] = cnt[i];
  lc[t] = 0;
  __syncthreads();
  // ebeg = sum of bucket counts before b (parallel partial + tree reduce)
  int partial = 0;
  for (int i = t; i < b; i += 256) partial += bc[i];
  sd[t] = partial;
  __syncthreads();
  for (int off = 128; off > 0; off >>= 1) {
    if (t < off) sd[t] += sd[t + off];
    __syncthreads();
  }
  const int ebeg = sd[0];
  const int myCnt = bc[b];
  __syncthreads();
  const unsigned* pb = pairArr + (size_t)b * CAP;
  for (int i = t; i < myCnt; i += 256)
    atomicAdd(&lc[pb[i] & 255u], 1);
  __syncthreads();
  const int v = lc[t];
  sd[t] = v;
  __syncthreads();
  for (int off = 1; off < 256; off <<= 1) {
    int x = (t >= off) ? sd[t - off] : 0;
    __syncthreads();
    sd[t] += x;
    __syncthreads();
  }
  const int excl = sd[t] - v;  // exclusive within bucket
  lc[t] = excl;                // cursor
  const int node = n0 + t;
  if (node < NN) {
    rowptr[node] = ebeg + excl;
    dinv[node] = rsqrtf(1.0f + (float)v);  // self-loop => deg >= 1
  }
  if (b == 0 && t == 0) rowptr[NN] = NE;
  __syncthreads();
  for (int i = t; i < myCnt; i += 256) {
    unsigned p = pb[i];
    int d = (int)(p & 255u);
    int srcv = (int)(p >> 8);
    int pos = atomicAdd(&lc[d], 1);
    col[ebeg + pos] = srcv;
  }
}

// ---------------- MFMA GEMM (layer 1): hs1 = bf16( X @ W1 * dinv ) -----------

template <int COUT, bool FUSED>
__global__ __launch_bounds__(256) void k_gemmM(const ushortT* __restrict__ A,
                                               const float* __restrict__ X,
                                               const ushortT* __restrict__ Bp,
                                               const float* __restrict__ dinv,
                                               ushortT* __restrict__ hs) {
  constexpr int CGALL = COUT / 16;              // 8 or 4
  constexpr int RG = 2;                         // row-groups per wave (32 rows)
  constexpr int CG = 4;                         // col-groups per wave (64 cols)
  const int w = threadIdx.x >> 6;
  const int lane = threadIdx.x & 63;
  const int q = lane >> 4;
  const int c = lane & 15;
  int row0, cg0;
  if (COUT == 128) {
    row0 = blockIdx.x * 64 + (w & 1) * 32;     // block: 64 rows x 128 cols
    cg0 = (w >> 1) * 4;
  } else {
    row0 = blockIdx.x * 128 + w * 32;          // block: 128 rows x 64 cols
    cg0 = 0;
  }

  const ushortT* ap[RG];
  const float* xp[RG];
#pragma unroll
  for (int rg = 0; rg < RG; rg++) {
    const int row = row0 + rg * 16 + c;
    if (FUSED) xp[rg] = X + (size_t)min(row, NN - 1) * 128 + q * 8;
    else ap[rg] = A + (size_t)row * 128 + q * 8;
  }
  const ushortT* bp0 = Bp + (size_t)lane * 8;

  f4 acc[RG][CG];
#pragma unroll
  for (int i = 0; i < RG; i++)
#pragma unroll
    for (int j = 0; j < CG; j++) acc[i][j] = (f4){0.f, 0.f, 0.f, 0.f};

  sh8 ah[RG], bh[CG], bl[CG];
  sh8 nah[RG], nbh[CG], nbl[CG];

  auto loadA = [&](int kr, sh8 (&h)[RG]) {
#pragma unroll
    for (int rg = 0; rg < RG; rg++) {
      if (FUSED) {
        const float4 x0 = *reinterpret_cast<const float4*>(xp[rg] + kr * 32);
        const float4 x1 = *reinterpret_cast<const float4*>(xp[rg] + kr * 32 + 4);
        h[rg] = hi8(x0, x1);
      } else {
        h[rg] = *reinterpret_cast<const sh8*>(ap[rg] + kr * 32);
      }
    }
  };
  auto loadB = [&](int kr, sh8 (&h)[CG], sh8 (&l)[CG]) {
#pragma unroll
    for (int cg = 0; cg < CG; cg++) {
      h[cg] = *reinterpret_cast<const sh8*>(bp0 + (size_t)(kr * CGALL + cg0 + cg) * 512);
      l[cg] = *reinterpret_cast<const sh8*>(bp0 + (size_t)((4 + kr) * CGALL + cg0 + cg) * 512);
    }
  };

  loadA(0, ah);
  loadB(0, bh, bl);
#pragma unroll
  for (int kr = 0; kr < 4; kr++) {
    if (kr < 3) {
      loadA(kr + 1, nah);
      loadB(kr + 1, nbh, nbl);
    }
#pragma unroll
    for (int rg = 0; rg < RG; rg++)
#pragma unroll
      for (int cg = 0; cg < CG; cg++)
        acc[rg][cg] = __builtin_amdgcn_mfma_f32_16x16x32_bf16(ah[rg], bh[cg],
                                                              acc[rg][cg], 0, 0, 0);
#pragma unroll
    for (int rg = 0; rg < RG; rg++)
#pragma unroll
      for (int cg = 0; cg < CG; cg++)
        acc[rg][cg] = __builtin_amdgcn_mfma_f32_16x16x32_bf16(ah[rg], bl[cg],
                                                              acc[rg][cg], 0, 0, 0);
    if (kr < 3) {
#pragma unroll
      for (int rg = 0; rg < RG; rg++) ah[rg] = nah[rg];
#pragma unroll
      for (int cg = 0; cg < CG; cg++) { bh[cg] = nbh[cg]; bl[cg] = nbl[cg]; }
    }
  }

  // epilogue: scale by dinv[row], round to bf16, store
#pragma unroll
  for (int rg = 0; rg < RG; rg++) {
#pragma unroll
    for (int reg = 0; reg < 4; reg++) {
      const int row = row0 + rg * 16 + q * 4 + reg;
      if (row < NN) {
        const float dv = dinv[row];
#pragma unroll
        for (int cg = 0; cg < CG; cg++) {
          hs[(size_t)row * COUT + (cg0 + cg) * 16 + c] = bfr(acc[rg][cg][reg] * dv);
        }
      }
    }
  }
}

// ---------------- FUSED aggregate + next-layer GEMM (v2: 16 waves) ----------
// Block = 64 nodes, 1024 threads = 16 waves; wave w aggregates nodes
// nw0..nw0+3 (4 per wave — restores 25K gathering waves after R2's 6.2K
// starved HBM to 1.89 TB/s). rowptr[5]/dinv[4] prefetched per wave via
// lane-parallel load + shfl (kills per-node serial latency chain).
// Results relu(agg*dinv+bias) -> 16 KB LDS tile (bf16, XOR-swizzled
// byte^=((row&7)<<4)); one barrier; 16 waves MFMA the 64xCOUT tile against
// L2-hot Bp. Occupancy: 2 blocks/CU (thread-limited), LDS 2x16KB, VGPR<=64
// enforced. Saves 51.2 MB A round-trip + one GEMM dispatch per junction.

template <int COUT>
__global__ __launch_bounds__(1024, 8) void k_aggemm(
    const ushortT* __restrict__ hs_in, const int* __restrict__ rowptr,
    const int* __restrict__ col, const float* __restrict__ dinv,
    const float* __restrict__ bias, const ushortT* __restrict__ Bp,
    ushortT* __restrict__ hs_out) {
  constexpr int CGALL = COUT / 16;         // 8 or 4
  constexpr int UPW = (4 * CGALL) / 16;    // MFMA units per wave: 2 or 1
  __shared__ ushortT At[64 * 128];         // 16 KB bf16 tile, swizzled
  const int t = threadIdx.x;
  const int w = t >> 6;        // wave 0..15
  const int lane = t & 63;
  const int q = lane >> 4;
  const int c = lane & 15;
  const int chb = c * 8;
  const int n0 = blockIdx.x * 64;
  const int nw0 = n0 + w * 4;  // first node of this wave

  // ---- prefetch per-wave metadata (rowptr[0..4], dinv[0..3] of nw0) ----
  const int rpv = rowptr[min(nw0 + (lane & 7), NN)];      // lanes 0..4 useful
  const float dvv = dinv[min(nw0 + (lane & 3), NN - 1)];
  const float4 b0 = *reinterpret_cast<const float4*>(bias + chb);
  const float4 b1 = *reinterpret_cast<const float4*>(bias + chb + 4);

  // ---- phase 1: aggregate 4 nodes per wave into LDS ----
  for (int it = 0; it < 4; ++it) {
    const int node = nw0 + it;
    const int r = w * 4 + it;  // LDS row 0..63
    const int beg = __shfl(rpv, it);
    const int end = __shfl(rpv, it + 1);
    const float di = __shfl(dvv, it);
    float a[8] = {};
    if (node < NN && q == 0) {  // self-loop
      const uint4 v = *reinterpret_cast<const uint4*>(hs_in + (long)node * 128 + chb);
      acc8(v, a);
    }
    int j = beg;  // (node >= NN => beg == end == NE, loops skipped)
    if (j + 8 <= end) {
      int c0 = col[j + q];
      int c1 = col[j + 4 + q];
      while (true) {
        const uint4 v0 = *reinterpret_cast<const uint4*>(hs_in + (long)c0 * 128 + chb);
        const uint4 v1 = *reinterpret_cast<const uint4*>(hs_in + (long)c1 * 128 + chb);
        j += 8;
        const bool more = (j + 8 <= end);
        int m0, m1;
        if (more) { m0 = col[j + q]; m1 = col[j + 4 + q]; }
        acc8(v0, a);
        acc8(v1, a);
        if (!more) break;
        c0 = m0; c1 = m1;
      }
    }
    if (j + 4 <= end) {
      int cc = col[j + q];
      const uint4 v = *reinterpret_cast<const uint4*>(hs_in + (long)cc * 128 + chb);
      acc8(v, a);
      j += 4;
    }
    {
      const int rem = end - j;  // 0..3
      if (q < rem) {
        int cc = col[j + q];
        const uint4 v = *reinterpret_cast<const uint4*>(hs_in + (long)cc * 128 + chb);
        acc8(v, a);
      }
    }
#pragma unroll
    for (int i = 0; i < 8; i++) a[i] += __shfl(a[i], lane ^ 32);
#pragma unroll
    for (int i = 0; i < 8; i++) a[i] += __shfl(a[i], lane ^ 16);
    if (q == 0 && node < NN) {
      float o[8];
      o[0] = fmaf(a[0], di, b0.x); o[1] = fmaf(a[1], di, b0.y);
      o[2] = fmaf(a[2], di, b0.z); o[3] = fmaf(a[3], di, b0.w);
      o[4] = fmaf(a[4], di, b1.x); o[5] = fmaf(a[5], di, b1.y);
      o[6] = fmaf(a[6], di, b1.z); o[7] = fmaf(a[7], di, b1.w);
#pragma unroll
      for (int i = 0; i < 8; i++) o[i] = fmaxf(o[i], 0.f);  // relu (layers 1,2)
      uint4 H;
      H.x = (unsigned)bfr(o[0]) | ((unsigned)bfr(o[1]) << 16);
      H.y = (unsigned)bfr(o[2]) | ((unsigned)bfr(o[3]) << 16);
      H.z = (unsigned)bfr(o[4]) | ((unsigned)bfr(o[5]) << 16);
      H.w = (unsigned)bfr(o[6]) | ((unsigned)bfr(o[7]) << 16);
      const unsigned bo = (unsigned)(r * 256 + c * 16) ^ (unsigned)((r & 7) << 4);
      *reinterpret_cast<uint4*>(reinterpret_cast<char*>(At) + bo) = H;
    }
  }
  __syncthreads();

  // ---- phase 2: GEMM, wave w owns UPW col-groups of row-group rg ----
  const int rg = (w * UPW) / CGALL;   // 0..3 (16 rows each)
  const int cg0 = (w * UPW) % CGALL;
  const ushortT* bp0 = Bp + (size_t)lane * 8;
  const char* ab = reinterpret_cast<const char*>(At);
  const int arow = rg * 16 + c;  // A-frag row: m = lane&15
  f4 acc[UPW];
#pragma unroll
  for (int u = 0; u < UPW; ++u) acc[u] = (f4){0.f, 0.f, 0.f, 0.f};
#pragma unroll
  for (int kr = 0; kr < 4; ++kr) {
    const unsigned bo =
        (unsigned)(arow * 256 + kr * 64 + q * 16) ^ (unsigned)((arow & 7) << 4);
    const sh8 af = *reinterpret_cast<const sh8*>(ab + bo);
#pragma unroll
    for (int u = 0; u < UPW; ++u) {
      const sh8 bh = *reinterpret_cast<const sh8*>(
          bp0 + (size_t)(kr * CGALL + cg0 + u) * 512);
      acc[u] = __builtin_amdgcn_mfma_f32_16x16x32_bf16(af, bh, acc[u], 0, 0, 0);
    }
#pragma unroll
    for (int u = 0; u < UPW; ++u) {
      const sh8 bl = *reinterpret_cast<const sh8*>(
          bp0 + (size_t)((4 + kr) * CGALL + cg0 + u) * 512);
      acc[u] = __builtin_amdgcn_mfma_f32_16x16x32_bf16(af, bl, acc[u], 0, 0, 0);
    }
  }
  // epilogue: scale by dinv[row] (pre-scale for next agg), round, store
#pragma unroll
  for (int u = 0; u < UPW; ++u) {
#pragma unroll
    for (int reg = 0; reg < 4; ++reg) {
      const int row = n0 + rg * 16 + q * 4 + reg;  // C/D row = quad*4+reg [m89]
      if (row < NN) {
        hs_out[(size_t)row * COUT + (cg0 + u) * 16 + c] =
            bfr(acc[u][reg] * dinv[row]);
      }
    }
  }
}

// ---------------- final aggregation (64 ch, fp32 out) ------------------------

__global__ __launch_bounds__(256) void k_agg64(const ushortT* __restrict__ hs,
                                               const int* __restrict__ rowptr,
                                               const int* __restrict__ col,
                                               const float* __restrict__ dinv,
                                               const float* __restrict__ bias,
                                               float* __restrict__ out) {
  const int gid = blockIdx.x * 256 + threadIdx.x;
  const int node = gid >> 6;
  if (node >= NN) return;
  const int lane = threadIdx.x & 63;
  const int o8 = lane >> 3;        // eighth 0..7
  const int chb = (lane & 7) * 8;  // 8 channels per lane
  const int beg = rowptr[node];
  const int end = rowptr[node + 1];

  float a[8] = {};
  if (o8 == 0) {  // self
    const uint4 v = *reinterpret_cast<const uint4*>(hs + (long)node * 64 + chb);
    acc8(v, a);
  }

  int j = beg;
  if (j + 16 <= end) {
    int c0 = col[j + o8];
    int c1 = col[j + 8 + o8];
    while (true) {
      const uint4 v0 = *reinterpret_cast<const uint4*>(hs + (long)c0 * 64 + chb);
      const uint4 v1 = *reinterpret_cast<const uint4*>(hs + (long)c1 * 64 + chb);
      j += 16;
      const bool more = (j + 16 <= end);
      int n0, n1;
      if (more) { n0 = col[j + o8]; n1 = col[j + 8 + o8]; }
      acc8(v0, a);
      acc8(v1, a);
      if (!more) break;
      c0 = n0; c1 = n1;
    }
  }
  for (; j + 8 <= end; j += 8) {
    int c = col[j + o8];
    const uint4 v = *reinterpret_cast<const uint4*>(hs + (long)c * 64 + chb);
    acc8(v, a);
  }
  {
    const int r = end - j;  // 0..7
    if (o8 < r) {
      int c = col[j + o8];
      const uint4 v = *reinterpret_cast<const uint4*>(hs + (long)c * 64 + chb);
      acc8(v, a);
    }
  }

#pragma unroll
  for (int i = 0; i < 8; i++) a[i] += __shfl(a[i], lane ^ 32);
#pragma unroll
  for (int i = 0; i < 8; i++) a[i] += __shfl(a[i], lane ^ 16);
#pragma unroll
  for (int i = 0; i < 8; i++) a[i] += __shfl(a[i], lane ^ 8);

  if (o8 == 0) {
    const float di = dinv[node];
    const float4 b0 = *reinterpret_cast<const float4*>(bias + chb);
    const float4 b1 = *reinterpret_cast<const float4*>(bias + chb + 4);
    float4 r0, r1;
    r0.x = fmaf(a[0], di, b0.x); r0.y = fmaf(a[1], di, b0.y);
    r0.z = fmaf(a[2], di, b0.z); r0.w = fmaf(a[3], di, b0.w);
    r1.x = fmaf(a[4], di, b1.x); r1.y = fmaf(a[5], di, b1.y);
    r1.z = fmaf(a[6], di, b1.z); r1.w = fmaf(a[7], di, b1.w);
    *reinterpret_cast<float4*>(out + (long)node * 64 + chb) = r0;
    *reinterpret_cast<float4*>(out + (long)node * 64 + chb + 4) = r1;
  }
}

// ---------------- launch ----------------

extern "C" void kernel_launch(void* const* d_in, const int* in_sizes, int n_in,
                              void* d_out, int out_size, void* d_ws, size_t ws_size,
                              hipStream_t stream) {
  const float* x  = (const float*)d_in[0];
  const int* ei   = (const int*)d_in[1];
  const float* W1 = (const float*)d_in[2];
  const float* b1 = (const float*)d_in[3];
  const float* W2 = (const float*)d_in[4];
  const float* b2 = (const float*)d_in[5];
  const float* W3 = (const float*)d_in[6];
  const float* b3 = (const float*)d_in[7];
  float* out = (float*)d_out;
  const int* srcp = ei;        // edge_index[0]
  const int* dstp = ei + NE;   // edge_index[1]

  char* wsb = (char*)d_ws;
  size_t off = 0;
  auto alloc = [&](size_t bytes) -> void* {
    void* p = wsb + off;
    off += (bytes + 255) & ~(size_t)255;
    return p;
  };
  ushortT* hs1 = (ushortT*)alloc((size_t)MPAD * 128 * 2);  // bf16 layer-1 transform
  ushortT* hs2 = (ushortT*)alloc((size_t)NN * 128 * 2);    // bf16 layer-2 transform
  int*   col    = (int*)alloc((size_t)NE * 4);
  int*   rowptr = (int*)alloc((size_t)(NN + 1) * 4);
  float* dinv   = (float*)alloc((size_t)NN * 4);
  int*   cursor = (int*)alloc((size_t)NBK * 4);
  ushortT* Bp1 = (ushortT*)alloc((size_t)32768 * 2);  // 8 seg x 8 cg x 512
  ushortT* Bp2 = (ushortT*)alloc((size_t)32768 * 2);
  ushortT* Bp3 = (ushortT*)alloc((size_t)16384 * 2);  // 8 seg x 4 cg x 512
  // Aliases (sequential-kernel lifetimes):
  //   pairArr (391*5120*4 = 8 MB) lives in hs2: written K1, read K2,
  //     clobbered by k_aggemm<128>'s hs2 write (K4, after CSR done).
  //   hs3 (NN*64*2 = 12.8 MB) lives in hs1: hs1 dead after k_aggemm<128>
  //     reads it; k_aggemm<64> then writes hs3 there, k_agg64 reads it.
  unsigned* pairArr = (unsigned*)hs2;
  ushortT* hs3 = hs1;
  (void)ws_size; (void)in_sizes; (void)n_in; (void)out_size;

  hipMemsetAsync(cursor, 0, (size_t)NBK * 4, stream);
  k_scatterpack<<<SCB + 320, 256, 0, stream>>>(srcp, dstp, cursor, pairArr,
                                               W1, W2, W3, Bp1, Bp2, Bp3);
  k_buildcsr<<<NBK, 256, 0, stream>>>(pairArr, cursor, dinv, rowptr, col);

  const int aggGrid = (NN * 64) / 256;   // 25000
  const int gemmGrid128 = MPAD / 64;     // 1564 (64-row blocks)

  // layer 1 transform (fused X read)
  k_gemmM<128, true><<<gemmGrid128, 256, 0, stream>>>(nullptr, x, Bp1, dinv, hs1);
  // agg layer1 + transform layer2 (fused, 16-wave blocks)
  k_aggemm<128><<<NB64, 1024, 0, stream>>>(hs1, rowptr, col, dinv, b1, Bp2, hs2);
  // agg layer2 + transform layer3 (fused, 128 -> 64)
  k_aggemm<64><<<NB64, 1024, 0, stream>>>(hs2, rowptr, col, dinv, b2, Bp3, hs3);
  // final aggregation (no relu, fp32 out)
  k_agg64<<<aggGrid, 256, 0, stream>>>(hs3, rowptr, col, dinv, b3, out);
}

// Round 4
// 350.790 us; speedup vs baseline: 1.1023x; 1.0549x over previous
//
#include <hip/hip_runtime.h>

#define NN 100000
#define NE 1600000
#define NBK 391  // buckets of 256 nodes
#define BSH 8    // bucket = dst >> 8
#define MPAD 100096  // NN padded to 128-row tiles (782*128)
#define SCB 391      // ceil(NE/4096) scatter blocks
#define CAP 5120     // padded slots per bucket (expected max ~4.3K)
#define NB16 6250    // NN/16 fused agg+gemm blocks (exact)

typedef unsigned short ushortT;
typedef unsigned long long ull;
using sh8 = __attribute__((ext_vector_type(8))) short;   // 8 bf16 (4 VGPR) MFMA frag
using f4  = __attribute__((ext_vector_type(4))) float;   // MFMA accumulator

// ---------------- bf16 helpers ----------------

__device__ __forceinline__ unsigned short bfr(float f) {
  unsigned u = __float_as_uint(f);
  u += 0x7FFF + ((u >> 16) & 1);
  return (unsigned short)(u >> 16);
}
__device__ __forceinline__ float bf2f(unsigned short h) {
  return __uint_as_float(((unsigned)h) << 16);
}
__device__ __forceinline__ void acc8(const uint4 v, float* a) {
  a[0] += __uint_as_float(v.x << 16);
  a[1] += __uint_as_float(v.x & 0xFFFF0000u);
  a[2] += __uint_as_float(v.y << 16);
  a[3] += __uint_as_float(v.y & 0xFFFF0000u);
  a[4] += __uint_as_float(v.z << 16);
  a[5] += __uint_as_float(v.z & 0xFFFF0000u);
  a[6] += __uint_as_float(v.w << 16);
  a[7] += __uint_as_float(v.w & 0xFFFF0000u);
}
__device__ __forceinline__ sh8 hi8(const float4 a, const float4 b) {
  sh8 r;
  r[0] = (short)bfr(a.x); r[1] = (short)bfr(a.y);
  r[2] = (short)bfr(a.z); r[3] = (short)bfr(a.w);
  r[4] = (short)bfr(b.x); r[5] = (short)bfr(b.y);
  r[6] = (short)bfr(b.z); r[7] = (short)bfr(b.w);
  return r;
}

// ---------------- W pack helper ----------------
// Bp[((ks*CG + g)*64 + lane)*8 + j]; k=(ks&3)*32+(lane>>4)*8+j, n=g*16+(lane&15)
// hi for ks<4, lo residue for ks>=4.

template <int COUT>
__device__ __forceinline__ void packone(const float* __restrict__ W,
                                        ushortT* __restrict__ Bp, int i) {
  const int j = i & 7;
  const int l = (i >> 3) & 63;
  const int rest = i >> 9;
  const int g = rest % (COUT / 16);
  const int ks = rest / (COUT / 16);
  const int k = (ks & 3) * 32 + (l >> 4) * 8 + j;
  const int n = g * 16 + (l & 15);
  const float v = W[k * COUT + n];
  const unsigned short h = bfr(v);
  Bp[i] = (ks < 4) ? h : bfr(v - bf2f(h));
}

// ---------------- fused scatter (padded buckets) + weight pack ---------------
// Pairs packed to 4 B: (src << 8) | (dst & 255). src < 2^17, off 8 bits.

__global__ __launch_bounds__(256) void k_scatterpack(
    const int* __restrict__ src, const int* __restrict__ dst,
    int* __restrict__ cursor, unsigned* __restrict__ pairArr,
    const float* __restrict__ W1, const float* __restrict__ W2,
    const float* __restrict__ W3, ushortT* __restrict__ Bp1,
    ushortT* __restrict__ Bp2, ushortT* __restrict__ Bp3) {
  if (blockIdx.x >= SCB) {
    const int i = (blockIdx.x - SCB) * 256 + threadIdx.x;  // 0..81919
    if (i < 32768) packone<128>(W1, Bp1, i);
    else if (i < 65536) packone<128>(W2, Bp2, i - 32768);
    else packone<64>(W3, Bp3, i - 65536);
    return;
  }
  __shared__ int lcnt[512];   // NBK padded to 512 (zeros beyond) for paired scan
  __shared__ int lbase[512];
  __shared__ int lrank[NBK];
  __shared__ int bbase[NBK];
  __shared__ int sd2[256];
  __shared__ unsigned sorted[4096];
  __shared__ int target[4096];
  const int t = threadIdx.x;
  for (int i = t; i < 512; i += 256) lcnt[i] = 0;
  for (int i = t; i < NBK; i += 256) lrank[i] = 0;
  __syncthreads();
  const int base = blockIdx.x * 4096;
  int rs[16], rd[16];
#pragma unroll
  for (int q = 0; q < 16; q++) {
    int e = base + t + 256 * q;
    rs[q] = (e < NE) ? src[e] : -1;
    rd[q] = (e < NE) ? dst[e] : -1;
    if (rd[q] >= 0) atomicAdd(&lcnt[rd[q] >> BSH], 1);
  }
  __syncthreads();
  // 256-wide paired exclusive scan of lcnt[0..511]
  const int s0 = lcnt[2 * t];
  const int s1 = lcnt[2 * t + 1];
  sd2[t] = s0 + s1;
  __syncthreads();
  for (int off = 1; off < 256; off <<= 1) {
    int x = (t >= off) ? sd2[t - off] : 0;
    __syncthreads();
    sd2[t] += x;
    __syncthreads();
  }
  const int epair = sd2[t] - (s0 + s1);
  lbase[2 * t] = epair;
  lbase[2 * t + 1] = epair + s0;
  __syncthreads();
  for (int i = t; i < NBK; i += 256)
    if (lcnt[i] > 0) bbase[i] = atomicAdd(&cursor[i], lcnt[i]);
  __syncthreads();
#pragma unroll
  for (int q = 0; q < 16; q++) {
    if (rd[q] >= 0) {
      int b = rd[q] >> BSH;
      int r = atomicAdd(&lrank[b], 1);
      int slot = lbase[b] + r;
      sorted[slot] = ((unsigned)rs[q] << 8) | ((unsigned)rd[q] & 255u);
      target[slot] = b * CAP + bbase[b] + r;  // padded-bucket placement
    }
  }
  __syncthreads();
  const int n = min(4096, NE - base);
  for (int s = t; s < n; s += 256) pairArr[target[s]] = sorted[s];
}

// ---------------- CSR build: one block (256 thr) per 256-node bucket ---------

__global__ __launch_bounds__(256) void k_buildcsr(const unsigned* __restrict__ pairArr,
                                                  const int* __restrict__ cnt,
                                                  float* __restrict__ dinv,
                                                  int* __restrict__ rowptr,
                                                  int* __restrict__ col) {
  __shared__ int lc[256];
  __shared__ int sd[256];
  __shared__ int bc[NBK];
  const int t = threadIdx.x;
  const int b = blockIdx.x;
  const int n0 = b << BSH;
  for (int i = t; i < NBK; i += 256) bc[i] = cnt[i];
  lc[t] = 0;
  __syncthreads();
  // ebeg = sum of bucket counts before b (parallel partial + tree reduce)
  int partial = 0;
  for (int i = t; i < b; i += 256) partial += bc[i];
  sd[t] = partial;
  __syncthreads();
  for (int off = 128; off > 0; off >>= 1) {
    if (t < off) sd[t] += sd[t + off];
    __syncthreads();
  }
  const int ebeg = sd[0];
  const int myCnt = bc[b];
  __syncthreads();
  const unsigned* pb = pairArr + (size_t)b * CAP;
  for (int i = t; i < myCnt; i += 256)
    atomicAdd(&lc[pb[i] & 255u], 1);
  __syncthreads();
  const int v = lc[t];
  sd[t] = v;
  __syncthreads();
  for (int off = 1; off < 256; off <<= 1) {
    int x = (t >= off) ? sd[t - off] : 0;
    __syncthreads();
    sd[t] += x;
    __syncthreads();
  }
  const int excl = sd[t] - v;  // exclusive within bucket
  lc[t] = excl;                // cursor
  const int node = n0 + t;
  if (node < NN) {
    rowptr[node] = ebeg + excl;
    dinv[node] = rsqrtf(1.0f + (float)v);  // self-loop => deg >= 1
  }
  if (b == 0 && t == 0) rowptr[NN] = NE;
  __syncthreads();
  for (int i = t; i < myCnt; i += 256) {
    unsigned p = pb[i];
    int d = (int)(p & 255u);
    int srcv = (int)(p >> 8);
    int pos = atomicAdd(&lc[d], 1);
    col[ebeg + pos] = srcv;
  }
}

// ---------------- MFMA GEMM (layer 1): hs1 = bf16( X @ W1 * dinv ) -----------

template <int COUT, bool FUSED>
__global__ __launch_bounds__(256) void k_gemmM(const ushortT* __restrict__ A,
                                               const float* __restrict__ X,
                                               const ushortT* __restrict__ Bp,
                                               const float* __restrict__ dinv,
                                               ushortT* __restrict__ hs) {
  constexpr int CGALL = COUT / 16;              // 8 or 4
  constexpr int RG = 2;                         // row-groups per wave (32 rows)
  constexpr int CG = 4;                         // col-groups per wave (64 cols)
  const int w = threadIdx.x >> 6;
  const int lane = threadIdx.x & 63;
  const int q = lane >> 4;
  const int c = lane & 15;
  int row0, cg0;
  if (COUT == 128) {
    row0 = blockIdx.x * 64 + (w & 1) * 32;     // block: 64 rows x 128 cols
    cg0 = (w >> 1) * 4;
  } else {
    row0 = blockIdx.x * 128 + w * 32;          // block: 128 rows x 64 cols
    cg0 = 0;
  }

  const ushortT* ap[RG];
  const float* xp[RG];
#pragma unroll
  for (int rg = 0; rg < RG; rg++) {
    const int row = row0 + rg * 16 + c;
    if (FUSED) xp[rg] = X + (size_t)min(row, NN - 1) * 128 + q * 8;
    else ap[rg] = A + (size_t)row * 128 + q * 8;
  }
  const ushortT* bp0 = Bp + (size_t)lane * 8;

  f4 acc[RG][CG];
#pragma unroll
  for (int i = 0; i < RG; i++)
#pragma unroll
    for (int j = 0; j < CG; j++) acc[i][j] = (f4){0.f, 0.f, 0.f, 0.f};

  sh8 ah[RG], bh[CG], bl[CG];
  sh8 nah[RG], nbh[CG], nbl[CG];

  auto loadA = [&](int kr, sh8 (&h)[RG]) {
#pragma unroll
    for (int rg = 0; rg < RG; rg++) {
      if (FUSED) {
        const float4 x0 = *reinterpret_cast<const float4*>(xp[rg] + kr * 32);
        const float4 x1 = *reinterpret_cast<const float4*>(xp[rg] + kr * 32 + 4);
        h[rg] = hi8(x0, x1);
      } else {
        h[rg] = *reinterpret_cast<const sh8*>(ap[rg] + kr * 32);
      }
    }
  };
  auto loadB = [&](int kr, sh8 (&h)[CG], sh8 (&l)[CG]) {
#pragma unroll
    for (int cg = 0; cg < CG; cg++) {
      h[cg] = *reinterpret_cast<const sh8*>(bp0 + (size_t)(kr * CGALL + cg0 + cg) * 512);
      l[cg] = *reinterpret_cast<const sh8*>(bp0 + (size_t)((4 + kr) * CGALL + cg0 + cg) * 512);
    }
  };

  loadA(0, ah);
  loadB(0, bh, bl);
#pragma unroll
  for (int kr = 0; kr < 4; kr++) {
    if (kr < 3) {
      loadA(kr + 1, nah);
      loadB(kr + 1, nbh, nbl);
    }
#pragma unroll
    for (int rg = 0; rg < RG; rg++)
#pragma unroll
      for (int cg = 0; cg < CG; cg++)
        acc[rg][cg] = __builtin_amdgcn_mfma_f32_16x16x32_bf16(ah[rg], bh[cg],
                                                              acc[rg][cg], 0, 0, 0);
#pragma unroll
    for (int rg = 0; rg < RG; rg++)
#pragma unroll
      for (int cg = 0; cg < CG; cg++)
        acc[rg][cg] = __builtin_amdgcn_mfma_f32_16x16x32_bf16(ah[rg], bl[cg],
                                                              acc[rg][cg], 0, 0, 0);
    if (kr < 3) {
#pragma unroll
      for (int rg = 0; rg < RG; rg++) ah[rg] = nah[rg];
#pragma unroll
      for (int cg = 0; cg < CG; cg++) { bh[cg] = nbh[cg]; bl[cg] = nbl[cg]; }
    }
  }

  // epilogue: scale by dinv[row], round to bf16, store
#pragma unroll
  for (int rg = 0; rg < RG; rg++) {
#pragma unroll
    for (int reg = 0; reg < 4; reg++) {
      const int row = row0 + rg * 16 + q * 4 + reg;
      if (row < NN) {
        const float dv = dinv[row];
#pragma unroll
        for (int cg = 0; cg < CG; cg++) {
          hs[(size_t)row * COUT + (cg0 + cg) * 16 + c] = bfr(acc[rg][cg][reg] * dv);
        }
      }
    }
  }
}

// ---------------- FUSED aggregate + next-layer GEMM (v3: 256 thr / 16 nodes) -
// Block = 16 nodes, 256 threads = 4 waves; wave w aggregates 4 nodes (short
// serial chain), rowptr/dinv prefetched via lane-parallel load + shfl.
// 256-thr granularity restores the 8-blocks/CU staggered pipeline that hides
// per-block head/tail/barrier bubbles (R3's 1024-thr blocks = 2 slots/CU was
// the 0.72x scaler). Barrier scope = 4 waves. Results -> 4 KB swizzled LDS
// tile; GEMM: 16 rows x COUT, wave w covers UPW col-groups. Saves the 25.6 MB
// A round-trip per junction + one GEMM dispatch.

template <int COUT>
__global__ __launch_bounds__(256, 8) void k_aggemm(
    const ushortT* __restrict__ hs_in, const int* __restrict__ rowptr,
    const int* __restrict__ col, const float* __restrict__ dinv,
    const float* __restrict__ bias, const ushortT* __restrict__ Bp,
    ushortT* __restrict__ hs_out) {
  constexpr int CGALL = COUT / 16;   // 8 or 4
  constexpr int UPW = CGALL / 4;     // MFMA units per wave: 2 or 1
  __shared__ ushortT At[16 * 128];   // 4 KB bf16 tile, swizzled
  const int t = threadIdx.x;
  const int w = t >> 6;        // wave 0..3
  const int lane = t & 63;
  const int q = lane >> 4;
  const int c = lane & 15;
  const int chb = c * 8;
  const int n0 = blockIdx.x * 16;
  const int nw0 = n0 + w * 4;  // first node of this wave

  // ---- prefetch per-wave metadata (rowptr[0..4], dinv[0..3] of nw0) ----
  const int rpv = rowptr[min(nw0 + (lane & 7), NN)];      // lanes 0..4 useful
  const float dvv = dinv[min(nw0 + (lane & 3), NN - 1)];
  const float4 b0 = *reinterpret_cast<const float4*>(bias + chb);
  const float4 b1 = *reinterpret_cast<const float4*>(bias + chb + 4);

  // ---- phase 1: aggregate 4 nodes per wave into LDS ----
  for (int it = 0; it < 4; ++it) {
    const int node = nw0 + it;   // always < NN (NB16*16 == NN)
    const int r = w * 4 + it;    // LDS row 0..15
    const int beg = __shfl(rpv, it);
    const int end = __shfl(rpv, it + 1);
    const float di = __shfl(dvv, it);
    float a[8] = {};
    if (q == 0) {  // self-loop
      const uint4 v = *reinterpret_cast<const uint4*>(hs_in + (long)node * 128 + chb);
      acc8(v, a);
    }
    int j = beg;
    if (j + 8 <= end) {
      int c0 = col[j + q];
      int c1 = col[j + 4 + q];
      while (true) {
        const uint4 v0 = *reinterpret_cast<const uint4*>(hs_in + (long)c0 * 128 + chb);
        const uint4 v1 = *reinterpret_cast<const uint4*>(hs_in + (long)c1 * 128 + chb);
        j += 8;
        const bool more = (j + 8 <= end);
        int m0, m1;
        if (more) { m0 = col[j + q]; m1 = col[j + 4 + q]; }
        acc8(v0, a);
        acc8(v1, a);
        if (!more) break;
        c0 = m0; c1 = m1;
      }
    }
    if (j + 4 <= end) {
      int cc = col[j + q];
      const uint4 v = *reinterpret_cast<const uint4*>(hs_in + (long)cc * 128 + chb);
      acc8(v, a);
      j += 4;
    }
    {
      const int rem = end - j;  // 0..3
      if (q < rem) {
        int cc = col[j + q];
        const uint4 v = *reinterpret_cast<const uint4*>(hs_in + (long)cc * 128 + chb);
        acc8(v, a);
      }
    }
#pragma unroll
    for (int i = 0; i < 8; i++) a[i] += __shfl(a[i], lane ^ 32);
#pragma unroll
    for (int i = 0; i < 8; i++) a[i] += __shfl(a[i], lane ^ 16);
    if (q == 0) {
      float o[8];
      o[0] = fmaf(a[0], di, b0.x); o[1] = fmaf(a[1], di, b0.y);
      o[2] = fmaf(a[2], di, b0.z); o[3] = fmaf(a[3], di, b0.w);
      o[4] = fmaf(a[4], di, b1.x); o[5] = fmaf(a[5], di, b1.y);
      o[6] = fmaf(a[6], di, b1.z); o[7] = fmaf(a[7], di, b1.w);
#pragma unroll
      for (int i = 0; i < 8; i++) o[i] = fmaxf(o[i], 0.f);  // relu (layers 1,2)
      uint4 H;
      H.x = (unsigned)bfr(o[0]) | ((unsigned)bfr(o[1]) << 16);
      H.y = (unsigned)bfr(o[2]) | ((unsigned)bfr(o[3]) << 16);
      H.z = (unsigned)bfr(o[4]) | ((unsigned)bfr(o[5]) << 16);
      H.w = (unsigned)bfr(o[6]) | ((unsigned)bfr(o[7]) << 16);
      const unsigned bo = (unsigned)(r * 256 + c * 16) ^ (unsigned)((r & 7) << 4);
      *reinterpret_cast<uint4*>(reinterpret_cast<char*>(At) + bo) = H;
    }
  }
  __syncthreads();

  // ---- phase 2: GEMM, 16 rows x COUT; wave w owns col-groups w*UPW.. ----
  const int cg0 = w * UPW;
  const ushortT* bp0 = Bp + (size_t)lane * 8;
  const char* ab = reinterpret_cast<const char*>(At);
  const int arow = c;  // A-frag row: m = lane&15
  f4 acc[UPW];
#pragma unroll
  for (int u = 0; u < UPW; ++u) acc[u] = (f4){0.f, 0.f, 0.f, 0.f};
#pragma unroll
  for (int kr = 0; kr < 4; ++kr) {
    const unsigned bo =
        (unsigned)(arow * 256 + kr * 64 + q * 16) ^ (unsigned)((arow & 7) << 4);
    const sh8 af = *reinterpret_cast<const sh8*>(ab + bo);
#pragma unroll
    for (int u = 0; u < UPW; ++u) {
      const sh8 bh = *reinterpret_cast<const sh8*>(
          bp0 + (size_t)(kr * CGALL + cg0 + u) * 512);
      acc[u] = __builtin_amdgcn_mfma_f32_16x16x32_bf16(af, bh, acc[u], 0, 0, 0);
    }
#pragma unroll
    for (int u = 0; u < UPW; ++u) {
      const sh8 bl = *reinterpret_cast<const sh8*>(
          bp0 + (size_t)((4 + kr) * CGALL + cg0 + u) * 512);
      acc[u] = __builtin_amdgcn_mfma_f32_16x16x32_bf16(af, bl, acc[u], 0, 0, 0);
    }
  }
  // epilogue: scale by dinv[row] (pre-scale for next agg), round, store
#pragma unroll
  for (int reg = 0; reg < 4; ++reg) {
    const int row = n0 + q * 4 + reg;  // C/D row = quad*4+reg [m89]; < NN
    const float dv = dinv[row];
#pragma unroll
    for (int u = 0; u < UPW; ++u) {
      hs_out[(size_t)row * COUT + (cg0 + u) * 16 + c] = bfr(acc[u][reg] * dv);
    }
  }
}

// ---------------- final aggregation (64 ch, fp32 out) ------------------------

__global__ __launch_bounds__(256) void k_agg64(const ushortT* __restrict__ hs,
                                               const int* __restrict__ rowptr,
                                               const int* __restrict__ col,
                                               const float* __restrict__ dinv,
                                               const float* __restrict__ bias,
                                               float* __restrict__ out) {
  const int gid = blockIdx.x * 256 + threadIdx.x;
  const int node = gid >> 6;
  if (node >= NN) return;
  const int lane = threadIdx.x & 63;
  const int o8 = lane >> 3;        // eighth 0..7
  const int chb = (lane & 7) * 8;  // 8 channels per lane
  const int beg = rowptr[node];
  const int end = rowptr[node + 1];

  float a[8] = {};
  if (o8 == 0) {  // self
    const uint4 v = *reinterpret_cast<const uint4*>(hs + (long)node * 64 + chb);
    acc8(v, a);
  }

  int j = beg;
  if (j + 16 <= end) {
    int c0 = col[j + o8];
    int c1 = col[j + 8 + o8];
    while (true) {
      const uint4 v0 = *reinterpret_cast<const uint4*>(hs + (long)c0 * 64 + chb);
      const uint4 v1 = *reinterpret_cast<const uint4*>(hs + (long)c1 * 64 + chb);
      j += 16;
      const bool more = (j + 16 <= end);
      int n0, n1;
      if (more) { n0 = col[j + o8]; n1 = col[j + 8 + o8]; }
      acc8(v0, a);
      acc8(v1, a);
      if (!more) break;
      c0 = n0; c1 = n1;
    }
  }
  for (; j + 8 <= end; j += 8) {
    int c = col[j + o8];
    const uint4 v = *reinterpret_cast<const uint4*>(hs + (long)c * 64 + chb);
    acc8(v, a);
  }
  {
    const int r = end - j;  // 0..7
    if (o8 < r) {
      int c = col[j + o8];
      const uint4 v = *reinterpret_cast<const uint4*>(hs + (long)c * 64 + chb);
      acc8(v, a);
    }
  }

#pragma unroll
  for (int i = 0; i < 8; i++) a[i] += __shfl(a[i], lane ^ 32);
#pragma unroll
  for (int i = 0; i < 8; i++) a[i] += __shfl(a[i], lane ^ 16);
#pragma unroll
  for (int i = 0; i < 8; i++) a[i] += __shfl(a[i], lane ^ 8);

  if (o8 == 0) {
    const float di = dinv[node];
    const float4 b0 = *reinterpret_cast<const float4*>(bias + chb);
    const float4 b1 = *reinterpret_cast<const float4*>(bias + chb + 4);
    float4 r0, r1;
    r0.x = fmaf(a[0], di, b0.x); r0.y = fmaf(a[1], di, b0.y);
    r0.z = fmaf(a[2], di, b0.z); r0.w = fmaf(a[3], di, b0.w);
    r1.x = fmaf(a[4], di, b1.x); r1.y = fmaf(a[5], di, b1.y);
    r1.z = fmaf(a[6], di, b1.z); r1.w = fmaf(a[7], di, b1.w);
    *reinterpret_cast<float4*>(out + (long)node * 64 + chb) = r0;
    *reinterpret_cast<float4*>(out + (long)node * 64 + chb + 4) = r1;
  }
}

// ---------------- launch ----------------

extern "C" void kernel_launch(void* const* d_in, const int* in_sizes, int n_in,
                              void* d_out, int out_size, void* d_ws, size_t ws_size,
                              hipStream_t stream) {
  const float* x  = (const float*)d_in[0];
  const int* ei   = (const int*)d_in[1];
  const float* W1 = (const float*)d_in[2];
  const float* b1 = (const float*)d_in[3];
  const float* W2 = (const float*)d_in[4];
  const float* b2 = (const float*)d_in[5];
  const float* W3 = (const float*)d_in[6];
  const float* b3 = (const float*)d_in[7];
  float* out = (float*)d_out;
  const int* srcp = ei;        // edge_index[0]
  const int* dstp = ei + NE;   // edge_index[1]

  char* wsb = (char*)d_ws;
  size_t off = 0;
  auto alloc = [&](size_t bytes) -> void* {
    void* p = wsb + off;
    off += (bytes + 255) & ~(size_t)255;
    return p;
  };
  ushortT* hs1 = (ushortT*)alloc((size_t)MPAD * 128 * 2);  // bf16 layer-1 transform
  ushortT* hs2 = (ushortT*)alloc((size_t)NN * 128 * 2);    // bf16 layer-2 transform
  int*   col    = (int*)alloc((size_t)NE * 4);
  int*   rowptr = (int*)alloc((size_t)(NN + 1) * 4);
  float* dinv   = (float*)alloc((size_t)NN * 4);
  int*   cursor = (int*)alloc((size_t)NBK * 4);
  ushortT* Bp1 = (ushortT*)alloc((size_t)32768 * 2);  // 8 seg x 8 cg x 512
  ushortT* Bp2 = (ushortT*)alloc((size_t)32768 * 2);
  ushortT* Bp3 = (ushortT*)alloc((size_t)16384 * 2);  // 8 seg x 4 cg x 512
  // Aliases (sequential-kernel lifetimes):
  //   pairArr (391*5120*4 = 8 MB) lives in hs2: written K1, read K2,
  //     clobbered by k_aggemm<128>'s hs2 write (K4, after CSR done).
  //   hs3 (NN*64*2 = 12.8 MB) lives in hs1: hs1 dead after k_aggemm<128>
  //     reads it; k_aggemm<64> then writes hs3 there, k_agg64 reads it.
  unsigned* pairArr = (unsigned*)hs2;
  ushortT* hs3 = hs1;
  (void)ws_size; (void)in_sizes; (void)n_in; (void)out_size;

  hipMemsetAsync(cursor, 0, (size_t)NBK * 4, stream);
  k_scatterpack<<<SCB + 320, 256, 0, stream>>>(srcp, dstp, cursor, pairArr,
                                               W1, W2, W3, Bp1, Bp2, Bp3);
  k_buildcsr<<<NBK, 256, 0, stream>>>(pairArr, cursor, dinv, rowptr, col);

  const int aggGrid = (NN * 64) / 256;   // 25000
  const int gemmGrid128 = MPAD / 64;     // 1564 (64-row blocks)

  // layer 1 transform (fused X read)
  k_gemmM<128, true><<<gemmGrid128, 256, 0, stream>>>(nullptr, x, Bp1, dinv, hs1);
  // agg layer1 + transform layer2 (fused, 256-thr / 16-node blocks)
  k_aggemm<128><<<NB16, 256, 0, stream>>>(hs1, rowptr, col, dinv, b1, Bp2, hs2);
  // agg layer2 + transform layer3 (fused, 128 -> 64)
  k_aggemm<64><<<NB16, 256, 0, stream>>>(hs2, rowptr, col, dinv, b2, Bp3, hs3);
  // final aggregation (no relu, fp32 out)
  k_agg64<<<aggGrid, 256, 0, stream>>>(hs3, rowptr, col, dinv, b3, out);
}